// Round 9
// baseline (449.485 us; speedup 1.0000x reference)
//
#include <hip/hip_runtime.h>
#include <stdint.h>

typedef unsigned short u16;
typedef __bf16 bf16x8 __attribute__((ext_vector_type(8)));
typedef float f32x4 __attribute__((ext_vector_type(4)));
typedef unsigned short ushort8 __attribute__((ext_vector_type(8)));
typedef unsigned short ushort4v __attribute__((ext_vector_type(4)));

#define MFMA __builtin_amdgcn_mfma_f32_16x16x32_bf16
#define EXP2 __builtin_amdgcn_exp2f

__device__ __forceinline__ u16 f2bf(float f){
  uint32_t u = __builtin_bit_cast(uint32_t, f);
  u += 0x7fffu + ((u >> 16) & 1u);
  return (u16)(u >> 16);
}
__device__ __forceinline__ float bf2f(u16 h){
  uint32_t u = ((uint32_t)h) << 16;
  return __builtin_bit_cast(float, u);
}
__device__ __forceinline__ uint32_t cvtpk(float lo, float hi){
  uint32_t r;
  asm("v_cvt_pk_bf16_f32 %0, %1, %2" : "=v"(r) : "v"(lo), "v"(hi));
  return r;
}
__device__ __forceinline__ bf16x8 ld8(const u16* p){
  return __builtin_bit_cast(bf16x8, *(const ushort8*)p);
}
__device__ __forceinline__ void gload16(const void* g, void* l){
  __builtin_amdgcn_global_load_lds((__attribute__((address_space(1))) void*)(void*)g,
                                   (__attribute__((address_space(3))) void*)l, 16, 0, 0);
}

// ---------------- convert / transpose ----------------

__global__ __launch_bounds__(256) void k_conv8(const float* __restrict__ in, u16* __restrict__ out){
  int i = blockIdx.x*256 + threadIdx.x;   // 393216 threads, 8 elems each
  const float4* p = (const float4*)in;
  float4 a = p[i*2], b = p[i*2+1];
  ushort8 o;
  o[0]=f2bf(a.x); o[1]=f2bf(a.y); o[2]=f2bf(a.z); o[3]=f2bf(a.w);
  o[4]=f2bf(b.x); o[5]=f2bf(b.y); o[6]=f2bf(b.z); o[7]=f2bf(b.w);
  ((ushort8*)out)[i] = o;
}

// out[c][r] = in[r][c], f32 -> bf16.  grid (R/64, C/64), 256 thr
__global__ __launch_bounds__(256) void k_tr(const float* __restrict__ in, u16* __restrict__ out,
                                            int R, int Cc){
  __shared__ float tile[64][65];
  int r0 = blockIdx.x*64, c0 = blockIdx.y*64;
  int t = threadIdx.x;
  int c = t & 63, r4 = t >> 6;
  for (int i = 0; i < 16; ++i)
    tile[r4 + i*4][c] = in[(size_t)(r0 + r4 + i*4)*Cc + c0 + c];
  __syncthreads();
  for (int i = 0; i < 16; ++i){
    int rr = r4 + i*4;
    out[(size_t)(c0 + rr)*R + r0 + c] = f2bf(tile[c][rr]);
  }
}

// rel_pos tables * 8 (undo the q-prescale; log2e rides in via Qs), bf16, padded to 128 rows
__global__ __launch_bounds__(256) void k_relconv(const float* __restrict__ rh, const float* __restrict__ rw,
                                                 u16* __restrict__ rh8, u16* __restrict__ rw8){
  int i = blockIdx.x*256 + threadIdx.x;   // 16384
  if (i < 8192)      rh8[i] = f2bf(i < 8128 ? rh[i]*8.0f : 0.0f);
  else { int j = i - 8192; rw8[j] = f2bf(j < 8128 ? rw[j]*8.0f : 0.0f); }
}

// ---------------- QKV GEMM: (4096x768)x(768x2304), split to Qs/Kf/Vf ----------------
// K/V stored fragment-linear so every k_flash global load is a wave-contiguous 1KB burst:
//   Kf[h][kb][f=ct*2+ks][lane=lg*16+lr][e] = K[kb*64+ct*16+lr][ks*32+lg*8+e]
//   Vf[h][kb][f=dt*2+ks][lane=lg*16+lr][e] = V[kb*64+ks*32+lg*8+e][dt*16+lr]
// Each wave's 64x64 acc tile is exactly one Kf[h][kb] / Vf[h][kb] 4KB block,
// repacked through a per-wave LDS tile then written as 8x16B coalesced bursts.

__global__ __launch_bounds__(256) void k_qkv(const u16* __restrict__ X, const u16* __restrict__ WT,
                                             const float* __restrict__ bias,
                                             u16* __restrict__ Qs, u16* __restrict__ Kf, u16* __restrict__ Vf){
  __shared__ __align__(16) u16 At[128*64];
  __shared__ __align__(16) u16 Bt[128*64];
  __shared__ __align__(16) u16 Tt[4][64*72];   // per-wave repack tile, pad 72 keeps 16B align
  const int tid = threadIdx.x, lane = tid & 63, w = tid >> 6;
  const int m0 = blockIdx.x*128, n0 = blockIdx.y*128;
  const int wr = (w >> 1)*64, wc = (w & 1)*64;
  const int lr = lane & 15, lg = lane >> 4;
  const int srcRow = w*32 + (lane >> 3);
  const int srcK   = (lane & 7)*8;
  f32x4 acc[4][4] = {};
  for (int kt = 0; kt < 12; ++kt){
    const int kbase = kt*64;
    for (int s = 0; s < 4; ++s){
      gload16(X  + (size_t)(m0 + srcRow + s*8)*768 + kbase + srcK, At + (w*32 + s*8)*64);
      gload16(WT + (size_t)(n0 + srcRow + s*8)*768 + kbase + srcK, Bt + (w*32 + s*8)*64);
    }
    __syncthreads();
    bf16x8 af[2][4], bfr[2][4];
    for (int ks = 0; ks < 2; ++ks)
      for (int i = 0; i < 4; ++i){
        af[ks][i]  = ld8(At + (wr + i*16 + lr)*64 + ks*32 + lg*8);
        bfr[ks][i] = ld8(Bt + (wc + i*16 + lr)*64 + ks*32 + lg*8);
      }
    for (int ks = 0; ks < 2; ++ks)
      for (int mi = 0; mi < 4; ++mi)
        for (int ni = 0; ni < 4; ++ni)
          acc[mi][ni] = MFMA(af[ks][mi], bfr[ks][ni], acc[mi][ni], 0, 0, 0);
    __syncthreads();
  }
  const int colbase = n0 + wc;            // 64-aligned -> s3/hh uniform per wave
  const int s3 = colbase / 768;
  const int hh = (colbase % 768) >> 6;
  const int rowbase = m0 + wr;            // 64-aligned -> kb uniform per wave
  if (s3 == 0){
    for (int mi = 0; mi < 4; ++mi)
      for (int ni = 0; ni < 4; ++ni){
        float bv = bias[colbase + ni*16 + lr];
        for (int r = 0; r < 4; ++r){
          int row = rowbase + mi*16 + lg*4 + r;
          // Q pre-scaled by head_dim^-0.5 * log2(e) so softmax runs in exp2 domain
          Qs[((size_t)hh*4096 + row)*64 + ni*16 + lr] =
              f2bf((acc[mi][ni][r] + bv)*(0.125f*1.44269504f));
        }
      }
  } else {
    u16* T = Tt[w];
    for (int mi = 0; mi < 4; ++mi)
      for (int ni = 0; ni < 4; ++ni){
        float bv = bias[colbase + ni*16 + lr];
        for (int r = 0; r < 4; ++r){
          int row_l = mi*16 + lg*4 + r, col_l = ni*16 + lr;
          u16 v = f2bf(acc[mi][ni][r] + bv);
          if (s3 == 1) T[row_l*72 + col_l] = v;     // K: [token][d]
          else         T[col_l*72 + row_l] = v;     // V: [d][token] (transposed)
        }
      }
    // same-wave LDS write->read; no cross-wave sharing, compiler inserts lgkmcnt
    const int kb = rowbase >> 6;
    u16* dst = (s3 == 1 ? Kf : Vf) + ((size_t)hh*64 + kb)*4096 + lane*8;
    #pragma unroll
    for (int f = 0; f < 8; ++f){
      int a = f >> 1, ks = f & 1;
      *(ushort8*)&dst[f*512] = *(const ushort8*)&T[(a*16 + lr)*72 + ks*32 + lg*8];
    }
  }
}

// ---------------- rel_h / rel_w via MFMA; grid (64 qh, 12 h) ----------------

__global__ __launch_bounds__(256) void k_rel(const u16* __restrict__ Qs, const u16* __restrict__ Rh8,
                                             const u16* __restrict__ Rw8,
                                             u16* __restrict__ relh, u16* __restrict__ relw){
  __shared__ __align__(16) u16 Ql[64*64];
  __shared__ __align__(16) u16 Rhl[64*64];
  __shared__ __align__(16) u16 Rwl[128*64];
  const int tid = threadIdx.x, lane = tid & 63, w = tid >> 6;
  const int qh = blockIdx.x, h = blockIdx.y;
  const int lr = lane & 15, lg = lane >> 4;
  for (int j = 0; j < 2; ++j){
    int ch = tid + 256*j;             // 0..511
    int row = ch >> 3, k8 = (ch & 7)*8;
    *(ushort8*)&Ql[row*64 + k8]  = *(const ushort8*)&Qs[((size_t)h*4096 + qh*64 + row)*64 + k8];
    *(ushort8*)&Rhl[row*64 + k8] = *(const ushort8*)&Rh8[(qh + row)*64 + k8];
  }
  for (int j = 0; j < 4; ++j){
    int ch = tid + 256*j;             // 0..1023
    int row = ch >> 3, k8 = (ch & 7)*8;
    *(ushort8*)&Rwl[row*64 + k8] = *(const ushort8*)&Rw8[row*64 + k8];
  }
  __syncthreads();
  bf16x8 a[2];
  for (int ks = 0; ks < 2; ++ks) a[ks] = ld8(Ql + (w*16 + lr)*64 + ks*32 + lg*8);
  // rel_h[qw][kh] = (Q . rel_pos_h[qh+63-kh]) ; computed as Q @ Rh[qh+c]^T, kh = 63-c
  for (int ct = 0; ct < 4; ++ct){
    f32x4 c = {};
    for (int ks = 0; ks < 2; ++ks)
      c = MFMA(a[ks], ld8(Rhl + (ct*16 + lr)*64 + ks*32 + lg*8), c, 0, 0, 0);
    int kh = 63 - (ct*16 + lr);
    for (int r = 0; r < 4; ++r){
      int qw = w*16 + lg*4 + r;
      relh[((size_t)h*4096 + qh*64 + qw)*64 + kh] = f2bf(c[r]);
    }
  }
  // rel_w[qw][kw] = (Q . rel_pos_w[qw+63-kw]) ; full band, keep valid kw
  for (int ct = 0; ct < 8; ++ct){
    f32x4 c = {};
    for (int ks = 0; ks < 2; ++ks)
      c = MFMA(a[ks], ld8(Rwl + (ct*16 + lr)*64 + ks*32 + lg*8), c, 0, 0, 0);
    int cc = ct*16 + lr;
    for (int r = 0; r < 4; ++r){
      int qw = w*16 + lg*4 + r;
      int kw = qw + 63 - cc;
      if (kw >= 0 && kw < 64)
        relw[((size_t)h*4096 + qh*64 + qw)*64 + kw] = f2bf(c[r]);
    }
  }
}

// ---------------- flash attention; flat grid 768, 4 waves ----------------
// Block = 64 q-rows. Wave w: 32-row group (w>>1), KV half (w&1) of 32 tiles.
// Each wave processes TWO 16-row q-tiles (A/B) against SHARED K/V fragments:
// K/V loads per iter constant, compute doubled -> fixed per-tile costs
// (fragment loads, shfl-reduce latency, loop overhead) amortized 2x.
// Pairwise merge across KV halves through LDS at block end.
// Head->XCD affinity (768 = 8*96): <=2 heads (2MB KV) per XCD L2.
// Swapped operands: QK^T as mfma(K,Q)->S^T, PV as mfma(V^T,P^T)->O^T.
// launch_bounds(256,3): arch-VGPR budget ~80-170; (256,4) spills (R7: 350MB scratch).

// One 16-row q-tile step: QK^T + softmax + P pack/transpose + PV.  T is a
// literal (0/1) so all state indexing is compile-time (rule #20).
#define TILE_STEP(T, RHV, KC)                                                 \
  {                                                                           \
    f32x4 s[4];                                                               \
    _Pragma("unroll")                                                         \
    for (int ct = 0; ct < 4; ++ct){                                           \
      _Pragma("unroll")                                                       \
      for (int r = 0; r < 4; ++r) s[ct][r] = (RHV) + rwf[T][ct][r];           \
    }                                                                         \
    __builtin_amdgcn_s_setprio(1);                                            \
    _Pragma("unroll")                                                         \
    for (int ct = 0; ct < 4; ++ct){                                           \
      s[ct] = MFMA(KC[ct*2],   qf[T][0], s[ct], 0, 0, 0);                     \
      s[ct] = MFMA(KC[ct*2+1], qf[T][1], s[ct], 0, 0, 0);                     \
    }                                                                         \
    __builtin_amdgcn_s_setprio(0);                                            \
    float t0 = fmaxf(fmaxf(s[0][0], s[0][1]), fmaxf(s[0][2], s[0][3]));       \
    float t1 = fmaxf(fmaxf(s[1][0], s[1][1]), fmaxf(s[1][2], s[1][3]));       \
    float t2 = fmaxf(fmaxf(s[2][0], s[2][1]), fmaxf(s[2][2], s[2][3]));       \
    float t3 = fmaxf(fmaxf(s[3][0], s[3][1]), fmaxf(s[3][2], s[3][3]));       \
    float pm = fmaxf(fmaxf(t0, t1), fmaxf(t2, t3));                           \
    pm = fmaxf(pm, __shfl_xor(pm, 16, 64));                                   \
    pm = fmaxf(pm, __shfl_xor(pm, 32, 64));                                   \
    if (__any(pm > m[T])){                                                    \
      const float nm = fmaxf(m[T], pm);                                       \
      const float corr = EXP2(m[T] - nm);                                     \
      m[T] = nm;                                                              \
      lsum[T] *= corr;                                                        \
      _Pragma("unroll")                                                       \
      for (int dt = 0; dt < 4; ++dt)                                          \
        _Pragma("unroll")                                                     \
        for (int r = 0; r < 4; ++r) oacc[T][dt][r] *= corr;                   \
    }                                                                         \
    float rs = 0.f;                                                           \
    _Pragma("unroll")                                                         \
    for (int ct = 0; ct < 4; ++ct){                                           \
      _Pragma("unroll")                                                       \
      for (int r = 0; r < 4; ++r){                                            \
        float p2 = EXP2(s[ct][r] - m[T]);                                     \
        s[ct][r] = p2; rs += p2;                                              \
      }                                                                       \
    }                                                                         \
    rs += __shfl_xor(rs, 16, 64);                                             \
    rs += __shfl_xor(rs, 32, 64);                                             \
    lsum[T] += rs;                                                            \
    _Pragma("unroll")                                                         \
    for (int ct = 0; ct < 4; ++ct){                                           \
      uint2 uv;                                                               \
      uv.x = cvtpk(s[ct][0], s[ct][1]);                                       \
      uv.y = cvtpk(s[ct][2], s[ct][3]);                                       \
      *(uint2*)(Pb + ((lr*128 + ct*32 + lg*8) ^ swz)) = uv;                   \
    }                                                                         \
    bf16x8 pa0 = __builtin_bit_cast(bf16x8, *(ushort8*)(Pb + ((lr*128      + lg*16) ^ swz))); \
    bf16x8 pa1 = __builtin_bit_cast(bf16x8, *(ushort8*)(Pb + ((lr*128 + 64 + lg*16) ^ swz))); \
    __builtin_amdgcn_s_setprio(1);                                            \
    _Pragma("unroll")                                                         \
    for (int dt = 0; dt < 4; ++dt){                                           \
      oacc[T][dt] = MFMA(vv[dt*2],   pa0, oacc[T][dt], 0, 0, 0);              \
      oacc[T][dt] = MFMA(vv[dt*2+1], pa1, oacc[T][dt], 0, 0, 0);              \
    }                                                                         \
    __builtin_amdgcn_s_setprio(0);                                            \
  }

__global__ __launch_bounds__(256, 3) void k_flash(const u16* __restrict__ Qs, const u16* __restrict__ Kf,
                                                  const u16* __restrict__ Vf,
                                                  const u16* __restrict__ relh, const u16* __restrict__ relw,
                                                  u16* __restrict__ Ob){
  __shared__ __align__(16) char Psm[4][2048];     // per-wave P tile, XOR-swizzled
  __shared__ __align__(16) float Osm[4][32*68];   // per-wave O^T partial [q][d], pad 68
  __shared__ float MLsm[4][64];                   // per-wave m[32], l[32]
  const int tid = threadIdx.x, lane = tid & 63, w = tid >> 6;
  const int b = blockIdx.x;
  const int p = (b & 7)*96 + (b >> 3);         // head->XCD affinity remap (768 = 8*96)
  const int h = p >> 6, qg = p & 63;           // qg: 64-row group within head
  const int qt2 = w >> 1, half = w & 1;
  const int lr = lane & 15, lg = lane >> 4;
  const size_t hq = (size_t)h*4096;
  const int qbase = qg*64 + qt2*32;            // wave's 32 rows
  const int qA = qbase + lr, qB = qbase + 16 + lr;
  char* Pb = Psm[w];
  const int swz = (lr & 7) << 4;

  bf16x8 qf[2][2];
  qf[0][0] = ld8(Qs + (hq + qA)*64 + lg*8);
  qf[0][1] = ld8(Qs + (hq + qA)*64 + 32 + lg*8);
  qf[1][0] = ld8(Qs + (hq + qB)*64 + lg*8);
  qf[1][1] = ld8(Qs + (hq + qB)*64 + 32 + lg*8);
  // rel_w bias rows unpacked to f32 once
  float rwf[2][4][4];
  #pragma unroll
  for (int ct = 0; ct < 4; ++ct){
    ushort4v ta = *(const ushort4v*)&relw[(hq + qA)*64 + ct*16 + lg*4];
    ushort4v tb = *(const ushort4v*)&relw[(hq + qB)*64 + ct*16 + lg*4];
    #pragma unroll
    for (int r = 0; r < 4; ++r){ rwf[0][ct][r] = bf2f(ta[r]); rwf[1][ct][r] = bf2f(tb[r]); }
  }

  const u16* KfH = Kf + (size_t)h*262144 + lane*8;   // + kb*4096 + f*512
  const u16* VfH = Vf + (size_t)h*262144 + lane*8;
  const u16* rhA = relh + (hq + qA)*64;
  const u16* rhB = relh + (hq + qB)*64;

  float m[2] = {-1e30f, -1e30f}, lsum[2] = {0.f, 0.f};
  f32x4 oacc[2][4] = {};                       // O^T: rows d = dt*16+lg*4+r, col q = lr
  bf16x8 kA_[8], kB_[8], vv[8];
  const int kb0 = half*32;

  auto loadK = [&](bf16x8 (&dst)[8], int kbi){
    const u16* kp = KfH + kbi*4096;
    #pragma unroll
    for (int f = 0; f < 8; ++f) dst[f] = ld8(kp + f*512);
  };

#define ITER(KB, KN, KC, KNbuf)                                               \
  {                                                                           \
    const u16* vp = VfH + (KB)*4096;                                          \
    _Pragma("unroll")                                                         \
    for (int f = 0; f < 8; ++f) vv[f] = ld8(vp + f*512);                      \
    const float rhvA = bf2f(rhA[KB]);                                         \
    const float rhvB = bf2f(rhB[KB]);                                         \
    TILE_STEP(0, rhvA, KC)                                                    \
    loadK(KNbuf, KN);                                                         \
    TILE_STEP(1, rhvB, KC)                                                    \
  }

  loadK(kA_, kb0);
  for (int kl = 0; kl < 32; kl += 2){
    ITER(kb0 + kl,     kb0 + ((kl + 1) & 31), kA_, kB_)
    ITER(kb0 + kl + 1, kb0 + ((kl + 2) & 31), kB_, kA_)
  }
#undef ITER

  // ---- write partials, pairwise merge across KV halves ----
  {
    float* Ow = Osm[w];
    #pragma unroll
    for (int t = 0; t < 2; ++t)
      #pragma unroll
      for (int dt = 0; dt < 4; ++dt)
        *(f32x4*)&Ow[(t*16 + lr)*68 + dt*16 + lg*4] = oacc[t][dt];
    if (lg == 0){
      #pragma unroll
      for (int t = 0; t < 2; ++t){
        MLsm[w][t*16 + lr] = m[t];
        MLsm[w][32 + t*16 + lr] = lsum[t];
      }
    }
  }
  __syncthreads();
  {
    const int qg2 = tid >> 7;          // which 32-row group
    const int rr0 = (tid >> 3) & 15;   // rows rr0 and rr0+16
    const int dq  = tid & 7;
    const int w0 = qg2*2, w1 = w0 + 1;
    #pragma unroll
    for (int rw = 0; rw < 2; ++rw){
      const int rr = rr0 + rw*16;
      const float m0 = MLsm[w0][rr], m1 = MLsm[w1][rr];
      const float l0 = MLsm[w0][32 + rr], l1 = MLsm[w1][32 + rr];
      const float ms = fmaxf(m0, m1);
      const float s0 = EXP2(m0 - ms), s1 = EXP2(m1 - ms);
      const float inv = 1.0f / (s0*l0 + s1*l1);
      const float* O0 = &Osm[w0][rr*68 + dq*8];
      const float* O1 = &Osm[w1][rr*68 + dq*8];
      f32x4 a0 = *(const f32x4*)O0, a1 = *(const f32x4*)(O0 + 4);
      f32x4 b0 = *(const f32x4*)O1, b1 = *(const f32x4*)(O1 + 4);
      float v[8];
      #pragma unroll
      for (int j = 0; j < 4; ++j){
        v[j]     = (s0*a0[j] + s1*b0[j])*inv;
        v[j + 4] = (s0*a1[j] + s1*b1[j])*inv;
      }
      uint4 outv;
      outv.x = cvtpk(v[0], v[1]); outv.y = cvtpk(v[2], v[3]);
      outv.z = cvtpk(v[4], v[5]); outv.w = cvtpk(v[6], v[7]);
      const int qgl = qg*64 + qg2*32 + rr;
      *(uint4*)&Ob[(size_t)qgl*768 + h*64 + dq*8] = outv;
    }
  }
}

// ---------------- proj GEMM: (4096x768)x(768x768) + b -> f32 out ----------------

__global__ __launch_bounds__(256) void k_proj(const u16* __restrict__ A, const u16* __restrict__ WT,
                                              const float* __restrict__ bias, float* __restrict__ out){
  __shared__ __align__(16) u16 At[128*64];
  __shared__ __align__(16) u16 Bt[128*64];
  const int tid = threadIdx.x, lane = tid & 63, w = tid >> 6;
  const int m0 = blockIdx.x*128, n0 = blockIdx.y*128;
  const int wr = (w >> 1)*64, wc = (w & 1)*64;
  const int lr = lane & 15, lg = lane >> 4;
  const int srcRow = w*32 + (lane >> 3);
  const int srcK   = (lane & 7)*8;
  f32x4 acc[4][4] = {};
  for (int kt = 0; kt < 12; ++kt){
    const int kbase = kt*64;
    for (int s = 0; s < 4; ++s){
      gload16(A  + (size_t)(m0 + srcRow + s*8)*768 + kbase + srcK, At + (w*32 + s*8)*64);
      gload16(WT + (size_t)(n0 + srcRow + s*8)*768 + kbase + srcK, Bt + (w*32 + s*8)*64);
    }
    __syncthreads();
    bf16x8 af[2][4], bfr[2][4];
    for (int ks = 0; ks < 2; ++ks)
      for (int i = 0; i < 4; ++i){
        af[ks][i]  = ld8(At + (wr + i*16 + lr)*64 + ks*32 + lg*8);
        bfr[ks][i] = ld8(Bt + (wc + i*16 + lr)*64 + ks*32 + lg*8);
      }
    for (int ks = 0; ks < 2; ++ks)
      for (int mi = 0; mi < 4; ++mi)
        for (int ni = 0; ni < 4; ++ni)
          acc[mi][ni] = MFMA(af[ks][mi], bfr[ks][ni], acc[mi][ni], 0, 0, 0);
    __syncthreads();
  }
  for (int mi = 0; mi < 4; ++mi)
    for (int ni = 0; ni < 4; ++ni){
      int col = n0 + wc + ni*16 + lr;
      float bv = bias[col];
      for (int r = 0; r < 4; ++r){
        int row = m0 + wr + mi*16 + lg*4 + r;
        out[(size_t)row*768 + col] = acc[mi][ni][r] + bv;
      }
    }
}

// ---------------- launch ----------------

extern "C" void kernel_launch(void* const* d_in, const int* in_sizes, int n_in,
                              void* d_out, int out_size, void* d_ws, size_t ws_size,
                              hipStream_t stream){
  const float* X32   = (const float*)d_in[0];
  const float* qkvw  = (const float*)d_in[1];
  const float* qkvb  = (const float*)d_in[2];
  const float* projw = (const float*)d_in[3];
  const float* projb = (const float*)d_in[4];
  const float* rposh = (const float*)d_in[5];
  const float* rposw = (const float*)d_in[6];

  u16* Xb  = (u16*)d_ws;            // 4096*768
  u16* W1T = Xb  + 3145728;         // 2304*768
  u16* PT  = W1T + 1769472;         // 768*768
  u16* Rh8 = PT  + 589824;          // 128*64 (padded)
  u16* Rw8 = Rh8 + 8192;            // 128*64 (padded)
  u16* Qs  = Rw8 + 8192;            // 12*4096*64 (pre-scaled by 1/8 * log2e)
  u16* Kf  = Qs  + 3145728;         // fragment-linear K [12][64][8][64][8]
  u16* Vf  = Kf  + 3145728;         // fragment-linear V^T [12][64][8][64][8]
  u16* Rlh = Vf  + 3145728;         // [12][4096][64]
  u16* Rlw = Rlh + 3145728;         // [12][4096][64]
  u16* Ob  = Rlw + 3145728;         // [4096][768]
  float* out = (float*)d_out;

  k_conv8  <<<1536, 256, 0, stream>>>(X32, Xb);
  k_tr     <<<dim3(12, 36), 256, 0, stream>>>(qkvw, W1T, 768, 2304);
  k_tr     <<<dim3(12, 12), 256, 0, stream>>>(projw, PT, 768, 768);
  k_relconv<<<64, 256, 0, stream>>>(rposh, rposw, Rh8, Rw8);
  k_qkv    <<<dim3(32, 18), 256, 0, stream>>>(Xb, W1T, qkvb, Qs, Kf, Vf);
  k_rel    <<<dim3(64, 12), 256, 0, stream>>>(Qs, Rh8, Rw8, Rlh, Rlw);
  k_flash  <<<768, 256, 0, stream>>>(Qs, Kf, Vf, Rlh, Rlw, Ob);
  k_proj   <<<dim3(32, 6), 256, 0, stream>>>(Ob, PT, projb, out);
}

// Round 10
// 182.074 us; speedup vs baseline: 2.4687x; 2.4687x over previous
//
#include <hip/hip_runtime.h>
#include <stdint.h>

typedef unsigned short u16;
typedef __bf16 bf16x8 __attribute__((ext_vector_type(8)));
typedef float f32x4 __attribute__((ext_vector_type(4)));
typedef unsigned short ushort8 __attribute__((ext_vector_type(8)));
typedef unsigned short ushort4v __attribute__((ext_vector_type(4)));

#define MFMA __builtin_amdgcn_mfma_f32_16x16x32_bf16
#define EXP2 __builtin_amdgcn_exp2f

__device__ __forceinline__ u16 f2bf(float f){
  uint32_t u = __builtin_bit_cast(uint32_t, f);
  u += 0x7fffu + ((u >> 16) & 1u);
  return (u16)(u >> 16);
}
__device__ __forceinline__ float bf2f(u16 h){
  uint32_t u = ((uint32_t)h) << 16;
  return __builtin_bit_cast(float, u);
}
__device__ __forceinline__ uint32_t cvtpk(float lo, float hi){
  uint32_t r;
  asm("v_cvt_pk_bf16_f32 %0, %1, %2" : "=v"(r) : "v"(lo), "v"(hi));
  return r;
}
__device__ __forceinline__ bf16x8 ld8(const u16* p){
  return __builtin_bit_cast(bf16x8, *(const ushort8*)p);
}
__device__ __forceinline__ void gload16(const void* g, void* l){
  __builtin_amdgcn_global_load_lds((__attribute__((address_space(1))) void*)(void*)g,
                                   (__attribute__((address_space(3))) void*)l, 16, 0, 0);
}

// ---------------- convert / transpose ----------------

__global__ __launch_bounds__(256) void k_conv8(const float* __restrict__ in, u16* __restrict__ out){
  int i = blockIdx.x*256 + threadIdx.x;   // 393216 threads, 8 elems each
  const float4* p = (const float4*)in;
  float4 a = p[i*2], b = p[i*2+1];
  ushort8 o;
  o[0]=f2bf(a.x); o[1]=f2bf(a.y); o[2]=f2bf(a.z); o[3]=f2bf(a.w);
  o[4]=f2bf(b.x); o[5]=f2bf(b.y); o[6]=f2bf(b.z); o[7]=f2bf(b.w);
  ((ushort8*)out)[i] = o;
}

// out[c][r] = in[r][c], f32 -> bf16.  grid (R/64, C/64), 256 thr
__global__ __launch_bounds__(256) void k_tr(const float* __restrict__ in, u16* __restrict__ out,
                                            int R, int Cc){
  __shared__ float tile[64][65];
  int r0 = blockIdx.x*64, c0 = blockIdx.y*64;
  int t = threadIdx.x;
  int c = t & 63, r4 = t >> 6;
  for (int i = 0; i < 16; ++i)
    tile[r4 + i*4][c] = in[(size_t)(r0 + r4 + i*4)*Cc + c0 + c];
  __syncthreads();
  for (int i = 0; i < 16; ++i){
    int rr = r4 + i*4;
    out[(size_t)(c0 + rr)*R + r0 + c] = f2bf(tile[c][rr]);
  }
}

// rel_pos tables * 8 (undo the q-prescale; log2e rides in via Qs), bf16, padded to 128 rows
__global__ __launch_bounds__(256) void k_relconv(const float* __restrict__ rh, const float* __restrict__ rw,
                                                 u16* __restrict__ rh8, u16* __restrict__ rw8){
  int i = blockIdx.x*256 + threadIdx.x;   // 16384
  if (i < 8192)      rh8[i] = f2bf(i < 8128 ? rh[i]*8.0f : 0.0f);
  else { int j = i - 8192; rw8[j] = f2bf(j < 8128 ? rw[j]*8.0f : 0.0f); }
}

// ---------------- QKV GEMM: (4096x768)x(768x2304), split to Qs/Kf/Vf ----------------
// K/V stored fragment-linear so k_flash staging is pure contiguous bursts:
//   Kf[h][kb][f=ct*2+ks][lane=lg*16+lr][e] = K[kb*64+ct*16+lr][ks*32+lg*8+e]
//   Vf[h][kb][f=dt*2+ks][lane=lg*16+lr][e] = V[kb*64+ks*32+lg*8+e][dt*16+lr]
// Each wave's 64x64 acc tile is exactly one Kf[h][kb] / Vf[h][kb] 8KB block,
// repacked through a per-wave LDS tile then written as 8x16B coalesced bursts.

__global__ __launch_bounds__(256) void k_qkv(const u16* __restrict__ X, const u16* __restrict__ WT,
                                             const float* __restrict__ bias,
                                             u16* __restrict__ Qs, u16* __restrict__ Kf, u16* __restrict__ Vf){
  __shared__ __align__(16) u16 At[128*64];
  __shared__ __align__(16) u16 Bt[128*64];
  __shared__ __align__(16) u16 Tt[4][64*72];   // per-wave repack tile, pad 72 keeps 16B align
  const int tid = threadIdx.x, lane = tid & 63, w = tid >> 6;
  const int m0 = blockIdx.x*128, n0 = blockIdx.y*128;
  const int wr = (w >> 1)*64, wc = (w & 1)*64;
  const int lr = lane & 15, lg = lane >> 4;
  const int srcRow = w*32 + (lane >> 3);
  const int srcK   = (lane & 7)*8;
  f32x4 acc[4][4] = {};
  for (int kt = 0; kt < 12; ++kt){
    const int kbase = kt*64;
    for (int s = 0; s < 4; ++s){
      gload16(X  + (size_t)(m0 + srcRow + s*8)*768 + kbase + srcK, At + (w*32 + s*8)*64);
      gload16(WT + (size_t)(n0 + srcRow + s*8)*768 + kbase + srcK, Bt + (w*32 + s*8)*64);
    }
    __syncthreads();
    bf16x8 af[2][4], bfr[2][4];
    for (int ks = 0; ks < 2; ++ks)
      for (int i = 0; i < 4; ++i){
        af[ks][i]  = ld8(At + (wr + i*16 + lr)*64 + ks*32 + lg*8);
        bfr[ks][i] = ld8(Bt + (wc + i*16 + lr)*64 + ks*32 + lg*8);
      }
    for (int ks = 0; ks < 2; ++ks)
      for (int mi = 0; mi < 4; ++mi)
        for (int ni = 0; ni < 4; ++ni)
          acc[mi][ni] = MFMA(af[ks][mi], bfr[ks][ni], acc[mi][ni], 0, 0, 0);
    __syncthreads();
  }
  const int colbase = n0 + wc;            // 64-aligned -> s3/hh uniform per wave
  const int s3 = colbase / 768;
  const int hh = (colbase % 768) >> 6;
  const int rowbase = m0 + wr;            // 64-aligned -> kb uniform per wave
  if (s3 == 0){
    for (int mi = 0; mi < 4; ++mi)
      for (int ni = 0; ni < 4; ++ni){
        float bv = bias[colbase + ni*16 + lr];
        for (int r = 0; r < 4; ++r){
          int row = rowbase + mi*16 + lg*4 + r;
          // Q pre-scaled by head_dim^-0.5 * log2(e) so softmax runs in exp2 domain
          Qs[((size_t)hh*4096 + row)*64 + ni*16 + lr] =
              f2bf((acc[mi][ni][r] + bv)*(0.125f*1.44269504f));
        }
      }
  } else {
    u16* T = Tt[w];
    for (int mi = 0; mi < 4; ++mi)
      for (int ni = 0; ni < 4; ++ni){
        float bv = bias[colbase + ni*16 + lr];
        for (int r = 0; r < 4; ++r){
          int row_l = mi*16 + lg*4 + r, col_l = ni*16 + lr;
          u16 v = f2bf(acc[mi][ni][r] + bv);
          if (s3 == 1) T[row_l*72 + col_l] = v;     // K: [token][d]
          else         T[col_l*72 + row_l] = v;     // V: [d][token] (transposed)
        }
      }
    // same-wave LDS write->read; no cross-wave sharing, compiler inserts lgkmcnt
    const int kb = rowbase >> 6;
    u16* dst = (s3 == 1 ? Kf : Vf) + ((size_t)hh*64 + kb)*4096 + lane*8;
    #pragma unroll
    for (int f = 0; f < 8; ++f){
      int a = f >> 1, ks = f & 1;
      *(ushort8*)&dst[f*512] = *(const ushort8*)&T[(a*16 + lr)*72 + ks*32 + lg*8];
    }
  }
}

// ---------------- rel_h / rel_w via MFMA; grid (64 qh, 12 h) ----------------

__global__ __launch_bounds__(256) void k_rel(const u16* __restrict__ Qs, const u16* __restrict__ Rh8,
                                             const u16* __restrict__ Rw8,
                                             u16* __restrict__ relh, u16* __restrict__ relw){
  __shared__ __align__(16) u16 Ql[64*64];
  __shared__ __align__(16) u16 Rhl[64*64];
  __shared__ __align__(16) u16 Rwl[128*64];
  const int tid = threadIdx.x, lane = tid & 63, w = tid >> 6;
  const int qh = blockIdx.x, h = blockIdx.y;
  const int lr = lane & 15, lg = lane >> 4;
  for (int j = 0; j < 2; ++j){
    int ch = tid + 256*j;             // 0..511
    int row = ch >> 3, k8 = (ch & 7)*8;
    *(ushort8*)&Ql[row*64 + k8]  = *(const ushort8*)&Qs[((size_t)h*4096 + qh*64 + row)*64 + k8];
    *(ushort8*)&Rhl[row*64 + k8] = *(const ushort8*)&Rh8[(qh + row)*64 + k8];
  }
  for (int j = 0; j < 4; ++j){
    int ch = tid + 256*j;             // 0..1023
    int row = ch >> 3, k8 = (ch & 7)*8;
    *(ushort8*)&Rwl[row*64 + k8] = *(const ushort8*)&Rw8[row*64 + k8];
  }
  __syncthreads();
  bf16x8 a[2];
  for (int ks = 0; ks < 2; ++ks) a[ks] = ld8(Ql + (w*16 + lr)*64 + ks*32 + lg*8);
  // rel_h[qw][kh] = (Q . rel_pos_h[qh+63-kh]) ; computed as Q @ Rh[qh+c]^T, kh = 63-c
  for (int ct = 0; ct < 4; ++ct){
    f32x4 c = {};
    for (int ks = 0; ks < 2; ++ks)
      c = MFMA(a[ks], ld8(Rhl + (ct*16 + lr)*64 + ks*32 + lg*8), c, 0, 0, 0);
    int kh = 63 - (ct*16 + lr);
    for (int r = 0; r < 4; ++r){
      int qw = w*16 + lg*4 + r;
      relh[((size_t)h*4096 + qh*64 + qw)*64 + kh] = f2bf(c[r]);
    }
  }
  // rel_w[qw][kw] = (Q . rel_pos_w[qw+63-kw]) ; full band, keep valid kw
  for (int ct = 0; ct < 8; ++ct){
    f32x4 c = {};
    for (int ks = 0; ks < 2; ++ks)
      c = MFMA(a[ks], ld8(Rwl + (ct*16 + lr)*64 + ks*32 + lg*8), c, 0, 0, 0);
    int cc = ct*16 + lr;
    for (int r = 0; r < 4; ++r){
      int qw = w*16 + lg*4 + r;
      int kw = qw + 63 - cc;
      if (kw >= 0 && kw < 64)
        relw[((size_t)h*4096 + qh*64 + qw)*64 + kw] = f2bf(c[r]);
    }
  }
}

// ---------------- flash attention; flat grid 768, 4 waves ----------------
// R10: KV tiles staged into LDS ONCE per block via global_load_lds and SHARED
// by all 4 waves (R5/R8 had each wave loading privately -> 4x L2 reads; per-CU
// demand ~23 TB/s of the 34.5 TB/s L2 ceiling = the stall). Double-buffered
// (16KB/tile x2), one barrier per tile; next-tile staging issued before the
// current tile's compute so the latency hides under MFMA+softmax.
// Frees ~50 VGPRs vs register-resident K/V (no kA/kB/vv) -> no spill at (256,3)
// (R6/R7/R9 lesson: arch-VGPR budget at (256,3) is ~85, spill shows as FETCH blowup).
// Swapped operands: QK^T as mfma(K,Q)->S^T, PV as mfma(V^T,P^T)->O^T.
// Head->XCD affinity (768 = 8*96): <=2 heads (2MB KV) per XCD L2.

__global__ __launch_bounds__(256, 3) void k_flash(const u16* __restrict__ Qs, const u16* __restrict__ Kf,
                                                  const u16* __restrict__ Vf,
                                                  const u16* __restrict__ relh, const u16* __restrict__ relw,
                                                  u16* __restrict__ Ob){
  __shared__ __align__(16) u16 Kl[2][4096];       // 8KB per K tile (fragment-linear copy)
  __shared__ __align__(16) u16 Vl[2][4096];       // 8KB per V tile
  __shared__ __align__(16) char Psm[4][2048];     // per-wave P tile, XOR-swizzled
  const int tid = threadIdx.x, lane = tid & 63, w = tid >> 6;
  const int b = blockIdx.x;
  const int p = (b & 7)*96 + (b >> 3);         // head->XCD affinity remap (768 = 8*96)
  const int h = p >> 6, qb = p & 63;
  const int lr = lane & 15, lg = lane >> 4;
  const size_t hq = (size_t)h*4096;
  const int q = qb*64 + w*16 + lr;             // this lane's q row (S^T column)
  char* Pb = Psm[w];
  const int swz = (lr & 7) << 4;

  const bf16x8 qf0 = ld8(Qs + (hq + q)*64 + lg*8);
  const bf16x8 qf1 = ld8(Qs + (hq + q)*64 + 32 + lg*8);
  // rel_w bias row unpacked to f32 once
  float rwf[4][4];
  #pragma unroll
  for (int ct = 0; ct < 4; ++ct){
    ushort4v t = *(const ushort4v*)&relw[(hq + q)*64 + ct*16 + lg*4];
    #pragma unroll
    for (int r = 0; r < 4; ++r) rwf[ct][r] = bf2f(t[r]);
  }

  const u16* KfH = Kf + (size_t)h*262144;      // + kb*4096
  const u16* VfH = Vf + (size_t)h*262144;
  const u16* rhbase = relh + (hq + q)*64;

  float m = -1e30f, lsum = 0.f;
  f32x4 oacc[4] = {};                          // O^T: rows d = dt*16+lg*4+r, col q = lr

  // wave w stages 1KB chunks {2w, 2w+1} of K and V (8 chunks each, 4 waves).
  // global src per-lane (+lane*8 elems); LDS dest wave-uniform (HW adds lane*16B).
  auto stage = [&](int buf, int kb){
    const u16* ks = KfH + kb*4096 + w*1024 + lane*8;
    const u16* vs = VfH + kb*4096 + w*1024 + lane*8;
    gload16(ks,       &Kl[buf][w*1024]);
    gload16(ks + 512, &Kl[buf][w*1024 + 512]);
    gload16(vs,       &Vl[buf][w*1024]);
    gload16(vs + 512, &Vl[buf][w*1024 + 512]);
  };

#define ITERBODY(KB, BUF)                                                     \
  {                                                                           \
    const u16* KL = Kl[BUF] + lane*8;                                         \
    const u16* VL = Vl[BUF] + lane*8;                                         \
    const float rhv = bf2f(rhbase[KB]);                                       \
    f32x4 s[4];                                                               \
    _Pragma("unroll")                                                         \
    for (int ct = 0; ct < 4; ++ct){                                           \
      _Pragma("unroll")                                                       \
      for (int r = 0; r < 4; ++r) s[ct][r] = rhv + rwf[ct][r];                \
    }                                                                         \
    __builtin_amdgcn_s_setprio(1);                                            \
    _Pragma("unroll")                                                         \
    for (int ct = 0; ct < 4; ++ct){                                           \
      s[ct] = MFMA(ld8(KL + (ct*2)*512),   qf0, s[ct], 0, 0, 0);              \
      s[ct] = MFMA(ld8(KL + (ct*2+1)*512), qf1, s[ct], 0, 0, 0);              \
    }                                                                         \
    __builtin_amdgcn_s_setprio(0);                                            \
    float t0 = fmaxf(fmaxf(s[0][0], s[0][1]), fmaxf(s[0][2], s[0][3]));       \
    float t1 = fmaxf(fmaxf(s[1][0], s[1][1]), fmaxf(s[1][2], s[1][3]));       \
    float t2 = fmaxf(fmaxf(s[2][0], s[2][1]), fmaxf(s[2][2], s[2][3]));       \
    float t3 = fmaxf(fmaxf(s[3][0], s[3][1]), fmaxf(s[3][2], s[3][3]));       \
    float pm = fmaxf(fmaxf(t0, t1), fmaxf(t2, t3));                           \
    pm = fmaxf(pm, __shfl_xor(pm, 16, 64));                                   \
    pm = fmaxf(pm, __shfl_xor(pm, 32, 64));                                   \
    if (__any(pm > m)){                                                       \
      const float nm = fmaxf(m, pm);                                          \
      const float corr = EXP2(m - nm);                                        \
      m = nm;                                                                 \
      lsum *= corr;                                                           \
      _Pragma("unroll")                                                       \
      for (int dt = 0; dt < 4; ++dt)                                          \
        _Pragma("unroll")                                                     \
        for (int r = 0; r < 4; ++r) oacc[dt][r] *= corr;                      \
    }                                                                         \
    float rs = 0.f;                                                           \
    _Pragma("unroll")                                                         \
    for (int ct = 0; ct < 4; ++ct){                                           \
      _Pragma("unroll")                                                       \
      for (int r = 0; r < 4; ++r){                                            \
        float p2 = EXP2(s[ct][r] - m);                                        \
        s[ct][r] = p2; rs += p2;                                              \
      }                                                                       \
    }                                                                         \
    rs += __shfl_xor(rs, 16, 64);                                             \
    rs += __shfl_xor(rs, 32, 64);                                             \
    lsum += rs;                                                               \
    _Pragma("unroll")                                                         \
    for (int ct = 0; ct < 4; ++ct){                                           \
      uint2 uv;                                                               \
      uv.x = cvtpk(s[ct][0], s[ct][1]);                                       \
      uv.y = cvtpk(s[ct][2], s[ct][3]);                                       \
      *(uint2*)(Pb + ((lr*128 + ct*32 + lg*8) ^ swz)) = uv;                   \
    }                                                                         \
    bf16x8 pa0 = __builtin_bit_cast(bf16x8, *(ushort8*)(Pb + ((lr*128      + lg*16) ^ swz))); \
    bf16x8 pa1 = __builtin_bit_cast(bf16x8, *(ushort8*)(Pb + ((lr*128 + 64 + lg*16) ^ swz))); \
    __builtin_amdgcn_s_setprio(1);                                            \
    _Pragma("unroll")                                                         \
    for (int dt = 0; dt < 4; ++dt){                                           \
      oacc[dt] = MFMA(ld8(VL + (dt*2)*512),   pa0, oacc[dt], 0, 0, 0);        \
      oacc[dt] = MFMA(ld8(VL + (dt*2+1)*512), pa1, oacc[dt], 0, 0, 0);        \
    }                                                                         \
    __builtin_amdgcn_s_setprio(0);                                            \
  }

  stage(0, 0);
  __syncthreads();                     // drains vmcnt -> tile 0 ready
  for (int kb2 = 0; kb2 < 64; kb2 += 2){
    stage(1, (kb2 + 1) & 63);          // issue next-tile loads (overlap compute)
    ITERBODY(kb2, 0)
    __syncthreads();                   // buf1 staged + all waves done with buf0
    stage(0, (kb2 + 2) & 63);
    ITERBODY(kb2 + 1, 1)
    __syncthreads();
  }
#undef ITERBODY

  const float inv = 1.0f / lsum;
  #pragma unroll
  for (int dt = 0; dt < 4; ++dt){
    ushort4v pk;
    #pragma unroll
    for (int r = 0; r < 4; ++r) pk[r] = f2bf(oacc[dt][r]*inv);
    *(ushort4v*)&Ob[(size_t)q*768 + h*64 + dt*16 + lg*4] = pk;
  }
}

// ---------------- proj GEMM: (4096x768)x(768x768) + b -> f32 out ----------------

__global__ __launch_bounds__(256) void k_proj(const u16* __restrict__ A, const u16* __restrict__ WT,
                                              const float* __restrict__ bias, float* __restrict__ out){
  __shared__ __align__(16) u16 At[128*64];
  __shared__ __align__(16) u16 Bt[128*64];
  const int tid = threadIdx.x, lane = tid & 63, w = tid >> 6;
  const int m0 = blockIdx.x*128, n0 = blockIdx.y*128;
  const int wr = (w >> 1)*64, wc = (w & 1)*64;
  const int lr = lane & 15, lg = lane >> 4;
  const int srcRow = w*32 + (lane >> 3);
  const int srcK   = (lane & 7)*8;
  f32x4 acc[4][4] = {};
  for (int kt = 0; kt < 12; ++kt){
    const int kbase = kt*64;
    for (int s = 0; s < 4; ++s){
      gload16(A  + (size_t)(m0 + srcRow + s*8)*768 + kbase + srcK, At + (w*32 + s*8)*64);
      gload16(WT + (size_t)(n0 + srcRow + s*8)*768 + kbase + srcK, Bt + (w*32 + s*8)*64);
    }
    __syncthreads();
    bf16x8 af[2][4], bfr[2][4];
    for (int ks = 0; ks < 2; ++ks)
      for (int i = 0; i < 4; ++i){
        af[ks][i]  = ld8(At + (wr + i*16 + lr)*64 + ks*32 + lg*8);
        bfr[ks][i] = ld8(Bt + (wc + i*16 + lr)*64 + ks*32 + lg*8);
      }
    for (int ks = 0; ks < 2; ++ks)
      for (int mi = 0; mi < 4; ++mi)
        for (int ni = 0; ni < 4; ++ni)
          acc[mi][ni] = MFMA(af[ks][mi], bfr[ks][ni], acc[mi][ni], 0, 0, 0);
    __syncthreads();
  }
  for (int mi = 0; mi < 4; ++mi)
    for (int ni = 0; ni < 4; ++ni){
      int col = n0 + wc + ni*16 + lr;
      float bv = bias[col];
      for (int r = 0; r < 4; ++r){
        int row = m0 + wr + mi*16 + lg*4 + r;
        out[(size_t)row*768 + col] = acc[mi][ni][r] + bv;
      }
    }
}

// ---------------- launch ----------------

extern "C" void kernel_launch(void* const* d_in, const int* in_sizes, int n_in,
                              void* d_out, int out_size, void* d_ws, size_t ws_size,
                              hipStream_t stream){
  const float* X32   = (const float*)d_in[0];
  const float* qkvw  = (const float*)d_in[1];
  const float* qkvb  = (const float*)d_in[2];
  const float* projw = (const float*)d_in[3];
  const float* projb = (const float*)d_in[4];
  const float* rposh = (const float*)d_in[5];
  const float* rposw = (const float*)d_in[6];

  u16* Xb  = (u16*)d_ws;            // 4096*768
  u16* W1T = Xb  + 3145728;         // 2304*768
  u16* PT  = W1T + 1769472;         // 768*768
  u16* Rh8 = PT  + 589824;          // 128*64 (padded)
  u16* Rw8 = Rh8 + 8192;            // 128*64 (padded)
  u16* Qs  = Rw8 + 8192;            // 12*4096*64 (pre-scaled by 1/8 * log2e)
  u16* Kf  = Qs  + 3145728;         // fragment-linear K [12][64][8][64][8]
  u16* Vf  = Kf  + 3145728;         // fragment-linear V^T [12][64][8][64][8]
  u16* Rlh = Vf  + 3145728;         // [12][4096][64]
  u16* Rlw = Rlh + 3145728;         // [12][4096][64]
  u16* Ob  = Rlw + 3145728;         // [4096][768]
  float* out = (float*)d_out;

  k_conv8  <<<1536, 256, 0, stream>>>(X32, Xb);
  k_tr     <<<dim3(12, 36), 256, 0, stream>>>(qkvw, W1T, 768, 2304);
  k_tr     <<<dim3(12, 12), 256, 0, stream>>>(projw, PT, 768, 768);
  k_relconv<<<64, 256, 0, stream>>>(rposh, rposw, Rh8, Rw8);
  k_qkv    <<<dim3(32, 18), 256, 0, stream>>>(Xb, W1T, qkvb, Qs, Kf, Vf);
  k_rel    <<<dim3(64, 12), 256, 0, stream>>>(Qs, Rh8, Rw8, Rlh, Rlw);
  k_flash  <<<768, 256, 0, stream>>>(Qs, Kf, Vf, Rlh, Rlw, Ob);
  k_proj   <<<dim3(32, 6), 256, 0, stream>>>(Ob, PT, projb, out);
}

// Round 11
// 176.795 us; speedup vs baseline: 2.5424x; 1.0299x over previous
//
#include <hip/hip_runtime.h>
#include <stdint.h>

typedef unsigned short u16;
typedef __bf16 bf16x8 __attribute__((ext_vector_type(8)));
typedef float f32x4 __attribute__((ext_vector_type(4)));
typedef unsigned short ushort8 __attribute__((ext_vector_type(8)));
typedef unsigned short ushort4v __attribute__((ext_vector_type(4)));

#define MFMA __builtin_amdgcn_mfma_f32_16x16x32_bf16
#define EXP2 __builtin_amdgcn_exp2f

__device__ __forceinline__ u16 f2bf(float f){
  uint32_t u = __builtin_bit_cast(uint32_t, f);
  u += 0x7fffu + ((u >> 16) & 1u);
  return (u16)(u >> 16);
}
__device__ __forceinline__ float bf2f(u16 h){
  uint32_t u = ((uint32_t)h) << 16;
  return __builtin_bit_cast(float, u);
}
__device__ __forceinline__ uint32_t cvtpk(float lo, float hi){
  uint32_t r;
  asm("v_cvt_pk_bf16_f32 %0, %1, %2" : "=v"(r) : "v"(lo), "v"(hi));
  return r;
}
__device__ __forceinline__ bf16x8 ld8(const u16* p){
  return __builtin_bit_cast(bf16x8, *(const ushort8*)p);
}
__device__ __forceinline__ void gload16(const void* g, void* l){
  __builtin_amdgcn_global_load_lds((__attribute__((address_space(1))) void*)(void*)g,
                                   (__attribute__((address_space(3))) void*)l, 16, 0, 0);
}

// ---------------- convert / transpose ----------------

__global__ __launch_bounds__(256) void k_conv8(const float* __restrict__ in, u16* __restrict__ out){
  int i = blockIdx.x*256 + threadIdx.x;   // 393216 threads, 8 elems each
  const float4* p = (const float4*)in;
  float4 a = p[i*2], b = p[i*2+1];
  ushort8 o;
  o[0]=f2bf(a.x); o[1]=f2bf(a.y); o[2]=f2bf(a.z); o[3]=f2bf(a.w);
  o[4]=f2bf(b.x); o[5]=f2bf(b.y); o[6]=f2bf(b.z); o[7]=f2bf(b.w);
  ((ushort8*)out)[i] = o;
}

// out[c][r] = in[r][c], f32 -> bf16.  grid (R/64, C/64), 256 thr
__global__ __launch_bounds__(256) void k_tr(const float* __restrict__ in, u16* __restrict__ out,
                                            int R, int Cc){
  __shared__ float tile[64][65];
  int r0 = blockIdx.x*64, c0 = blockIdx.y*64;
  int t = threadIdx.x;
  int c = t & 63, r4 = t >> 6;
  for (int i = 0; i < 16; ++i)
    tile[r4 + i*4][c] = in[(size_t)(r0 + r4 + i*4)*Cc + c0 + c];
  __syncthreads();
  for (int i = 0; i < 16; ++i){
    int rr = r4 + i*4;
    out[(size_t)(c0 + rr)*R + r0 + c] = f2bf(tile[c][rr]);
  }
}

// rel_pos tables * 8 (undo the q-prescale; log2e rides in via Qs), bf16, padded to 128 rows
__global__ __launch_bounds__(256) void k_relconv(const float* __restrict__ rh, const float* __restrict__ rw,
                                                 u16* __restrict__ rh8, u16* __restrict__ rw8){
  int i = blockIdx.x*256 + threadIdx.x;   // 16384
  if (i < 8192)      rh8[i] = f2bf(i < 8128 ? rh[i]*8.0f : 0.0f);
  else { int j = i - 8192; rw8[j] = f2bf(j < 8128 ? rw[j]*8.0f : 0.0f); }
}

// ---------------- QKV GEMM: (4096x768)x(768x2304), split to Qs/Kf/Vf ----------------
// K/V stored fragment-linear so k_flash staging is pure contiguous bursts:
//   Kf[h][kb][f=ct*2+ks][lane=lg*16+lr][e] = K[kb*64+ct*16+lr][ks*32+lg*8+e]
//   Vf[h][kb][f=dt*2+ks][lane=lg*16+lr][e] = V[kb*64+ks*32+lg*8+e][dt*16+lr]
// Each wave's 64x64 acc tile is exactly one Kf[h][kb] / Vf[h][kb] 8KB block,
// repacked through a per-wave LDS tile then written as 8x16B coalesced bursts.

__global__ __launch_bounds__(256) void k_qkv(const u16* __restrict__ X, const u16* __restrict__ WT,
                                             const float* __restrict__ bias,
                                             u16* __restrict__ Qs, u16* __restrict__ Kf, u16* __restrict__ Vf){
  __shared__ __align__(16) u16 At[128*64];
  __shared__ __align__(16) u16 Bt[128*64];
  __shared__ __align__(16) u16 Tt[4][64*72];   // per-wave repack tile, pad 72 keeps 16B align
  const int tid = threadIdx.x, lane = tid & 63, w = tid >> 6;
  const int m0 = blockIdx.x*128, n0 = blockIdx.y*128;
  const int wr = (w >> 1)*64, wc = (w & 1)*64;
  const int lr = lane & 15, lg = lane >> 4;
  const int srcRow = w*32 + (lane >> 3);
  const int srcK   = (lane & 7)*8;
  f32x4 acc[4][4] = {};
  for (int kt = 0; kt < 12; ++kt){
    const int kbase = kt*64;
    for (int s = 0; s < 4; ++s){
      gload16(X  + (size_t)(m0 + srcRow + s*8)*768 + kbase + srcK, At + (w*32 + s*8)*64);
      gload16(WT + (size_t)(n0 + srcRow + s*8)*768 + kbase + srcK, Bt + (w*32 + s*8)*64);
    }
    __syncthreads();
    bf16x8 af[2][4], bfr[2][4];
    for (int ks = 0; ks < 2; ++ks)
      for (int i = 0; i < 4; ++i){
        af[ks][i]  = ld8(At + (wr + i*16 + lr)*64 + ks*32 + lg*8);
        bfr[ks][i] = ld8(Bt + (wc + i*16 + lr)*64 + ks*32 + lg*8);
      }
    for (int ks = 0; ks < 2; ++ks)
      for (int mi = 0; mi < 4; ++mi)
        for (int ni = 0; ni < 4; ++ni)
          acc[mi][ni] = MFMA(af[ks][mi], bfr[ks][ni], acc[mi][ni], 0, 0, 0);
    __syncthreads();
  }
  const int colbase = n0 + wc;            // 64-aligned -> s3/hh uniform per wave
  const int s3 = colbase / 768;
  const int hh = (colbase % 768) >> 6;
  const int rowbase = m0 + wr;            // 64-aligned -> kb uniform per wave
  if (s3 == 0){
    for (int mi = 0; mi < 4; ++mi)
      for (int ni = 0; ni < 4; ++ni){
        float bv = bias[colbase + ni*16 + lr];
        for (int r = 0; r < 4; ++r){
          int row = rowbase + mi*16 + lg*4 + r;
          // Q pre-scaled by head_dim^-0.5 * log2(e) so softmax runs in exp2 domain
          Qs[((size_t)hh*4096 + row)*64 + ni*16 + lr] =
              f2bf((acc[mi][ni][r] + bv)*(0.125f*1.44269504f));
        }
      }
  } else {
    u16* T = Tt[w];
    for (int mi = 0; mi < 4; ++mi)
      for (int ni = 0; ni < 4; ++ni){
        float bv = bias[colbase + ni*16 + lr];
        for (int r = 0; r < 4; ++r){
          int row_l = mi*16 + lg*4 + r, col_l = ni*16 + lr;
          u16 v = f2bf(acc[mi][ni][r] + bv);
          if (s3 == 1) T[row_l*72 + col_l] = v;     // K: [token][d]
          else         T[col_l*72 + row_l] = v;     // V: [d][token] (transposed)
        }
      }
    // same-wave LDS write->read; no cross-wave sharing, compiler inserts lgkmcnt
    const int kb = rowbase >> 6;
    u16* dst = (s3 == 1 ? Kf : Vf) + ((size_t)hh*64 + kb)*4096 + lane*8;
    #pragma unroll
    for (int f = 0; f < 8; ++f){
      int a = f >> 1, ks = f & 1;
      *(ushort8*)&dst[f*512] = *(const ushort8*)&T[(a*16 + lr)*72 + ks*32 + lg*8];
    }
  }
}

// ---------------- rel_h / rel_w via MFMA; grid (64 qh, 12 h) ----------------

__global__ __launch_bounds__(256) void k_rel(const u16* __restrict__ Qs, const u16* __restrict__ Rh8,
                                             const u16* __restrict__ Rw8,
                                             u16* __restrict__ relh, u16* __restrict__ relw){
  __shared__ __align__(16) u16 Ql[64*64];
  __shared__ __align__(16) u16 Rhl[64*64];
  __shared__ __align__(16) u16 Rwl[128*64];
  const int tid = threadIdx.x, lane = tid & 63, w = tid >> 6;
  const int qh = blockIdx.x, h = blockIdx.y;
  const int lr = lane & 15, lg = lane >> 4;
  for (int j = 0; j < 2; ++j){
    int ch = tid + 256*j;             // 0..511
    int row = ch >> 3, k8 = (ch & 7)*8;
    *(ushort8*)&Ql[row*64 + k8]  = *(const ushort8*)&Qs[((size_t)h*4096 + qh*64 + row)*64 + k8];
    *(ushort8*)&Rhl[row*64 + k8] = *(const ushort8*)&Rh8[(qh + row)*64 + k8];
  }
  for (int j = 0; j < 4; ++j){
    int ch = tid + 256*j;             // 0..1023
    int row = ch >> 3, k8 = (ch & 7)*8;
    *(ushort8*)&Rwl[row*64 + k8] = *(const ushort8*)&Rw8[row*64 + k8];
  }
  __syncthreads();
  bf16x8 a[2];
  for (int ks = 0; ks < 2; ++ks) a[ks] = ld8(Ql + (w*16 + lr)*64 + ks*32 + lg*8);
  // rel_h[qw][kh] = (Q . rel_pos_h[qh+63-kh]) ; computed as Q @ Rh[qh+c]^T, kh = 63-c
  for (int ct = 0; ct < 4; ++ct){
    f32x4 c = {};
    for (int ks = 0; ks < 2; ++ks)
      c = MFMA(a[ks], ld8(Rhl + (ct*16 + lr)*64 + ks*32 + lg*8), c, 0, 0, 0);
    int kh = 63 - (ct*16 + lr);
    for (int r = 0; r < 4; ++r){
      int qw = w*16 + lg*4 + r;
      relh[((size_t)h*4096 + qh*64 + qw)*64 + kh] = f2bf(c[r]);
    }
  }
  // rel_w[qw][kw] = (Q . rel_pos_w[qw+63-kw]) ; full band, keep valid kw
  for (int ct = 0; ct < 8; ++ct){
    f32x4 c = {};
    for (int ks = 0; ks < 2; ++ks)
      c = MFMA(a[ks], ld8(Rwl + (ct*16 + lr)*64 + ks*32 + lg*8), c, 0, 0, 0);
    int cc = ct*16 + lr;
    for (int r = 0; r < 4; ++r){
      int qw = w*16 + lg*4 + r;
      int kw = qw + 63 - cc;
      if (kw >= 0 && kw < 64)
        relw[((size_t)h*4096 + qh*64 + qw)*64 + kw] = f2bf(c[r]);
    }
  }
}

// ---------------- flash attention; flat grid 768, 4 waves ----------------
// R10 structure: KV tiles staged into LDS once per block (global_load_lds),
// shared by all 4 waves, double-buffered, 1 barrier/tile.
// R11: lazy softmax reductions (exact):
//  - cross-lane MAX reduce only inside the rare rescale branch; steady-state
//    detection uses lane-local max + wave-wide __any (row group is subset of wave).
//  - lsum kept per-lane; cross-lane SUM reduce done ONCE in the epilogue
//    (rescale corr is row-uniform so per-lane partials stay consistent).
// -> zero cross-lane ops in the steady-state iteration (was 4 dependent shfl chains).
// Swapped operands: QK^T as mfma(K,Q)->S^T, PV as mfma(V^T,P^T)->O^T.
// Head->XCD affinity (768 = 8*96): <=2 heads (2MB KV) per XCD L2.
// launch_bounds(256,3): arch-VGPR budget ~84 (R6/R7/R9: exceeding it shows as
// FETCH_SIZE blowup from scratch spill, NOT as a VGPR_Count change).

__global__ __launch_bounds__(256, 3) void k_flash(const u16* __restrict__ Qs, const u16* __restrict__ Kf,
                                                  const u16* __restrict__ Vf,
                                                  const u16* __restrict__ relh, const u16* __restrict__ relw,
                                                  u16* __restrict__ Ob){
  __shared__ __align__(16) u16 Kl[2][4096];       // 8KB per K tile (fragment-linear copy)
  __shared__ __align__(16) u16 Vl[2][4096];       // 8KB per V tile
  __shared__ __align__(16) char Psm[4][2048];     // per-wave P tile, XOR-swizzled
  const int tid = threadIdx.x, lane = tid & 63, w = tid >> 6;
  const int b = blockIdx.x;
  const int p = (b & 7)*96 + (b >> 3);         // head->XCD affinity remap (768 = 8*96)
  const int h = p >> 6, qb = p & 63;
  const int lr = lane & 15, lg = lane >> 4;
  const size_t hq = (size_t)h*4096;
  const int q = qb*64 + w*16 + lr;             // this lane's q row (S^T column)
  char* Pb = Psm[w];
  const int swz = (lr & 7) << 4;

  const bf16x8 qf0 = ld8(Qs + (hq + q)*64 + lg*8);
  const bf16x8 qf1 = ld8(Qs + (hq + q)*64 + 32 + lg*8);
  // rel_w bias row unpacked to f32 once
  float rwf[4][4];
  #pragma unroll
  for (int ct = 0; ct < 4; ++ct){
    ushort4v t = *(const ushort4v*)&relw[(hq + q)*64 + ct*16 + lg*4];
    #pragma unroll
    for (int r = 0; r < 4; ++r) rwf[ct][r] = bf2f(t[r]);
  }

  const u16* KfH = Kf + (size_t)h*262144;      // + kb*4096
  const u16* VfH = Vf + (size_t)h*262144;
  const u16* rhbase = relh + (hq + q)*64;

  float m = -1e30f, lsum = 0.f;                // lsum is PER-LANE partial (reduced at end)
  f32x4 oacc[4] = {};                          // O^T: rows d = dt*16+lg*4+r, col q = lr

  // wave w stages 1KB chunks {2w, 2w+1} of K and V (8 chunks each, 4 waves).
  // global src per-lane (+lane*8 elems); LDS dest wave-uniform (HW adds lane*16B).
  auto stage = [&](int buf, int kb){
    const u16* ks = KfH + kb*4096 + w*1024 + lane*8;
    const u16* vs = VfH + kb*4096 + w*1024 + lane*8;
    gload16(ks,       &Kl[buf][w*1024]);
    gload16(ks + 512, &Kl[buf][w*1024 + 512]);
    gload16(vs,       &Vl[buf][w*1024]);
    gload16(vs + 512, &Vl[buf][w*1024 + 512]);
  };

#define ITERBODY(KB, BUF)                                                     \
  {                                                                           \
    const u16* KL = Kl[BUF] + lane*8;                                         \
    const u16* VL = Vl[BUF] + lane*8;                                         \
    const float rhv = bf2f(rhbase[KB]);                                       \
    f32x4 s[4];                                                               \
    _Pragma("unroll")                                                         \
    for (int ct = 0; ct < 4; ++ct){                                           \
      _Pragma("unroll")                                                       \
      for (int r = 0; r < 4; ++r) s[ct][r] = rhv + rwf[ct][r];                \
    }                                                                         \
    __builtin_amdgcn_s_setprio(1);                                            \
    _Pragma("unroll")                                                         \
    for (int ct = 0; ct < 4; ++ct){                                           \
      s[ct] = MFMA(ld8(KL + (ct*2)*512),   qf0, s[ct], 0, 0, 0);              \
      s[ct] = MFMA(ld8(KL + (ct*2+1)*512), qf1, s[ct], 0, 0, 0);              \
    }                                                                         \
    __builtin_amdgcn_s_setprio(0);                                            \
    /* lane-local max over own 16 values (max3-friendly nesting) */           \
    float pm0 = fmaxf(fmaxf(s[0][0], s[0][1]), fmaxf(fmaxf(s[0][2], s[0][3]), \
                      fmaxf(s[1][0], s[1][1])));                              \
    float pm1 = fmaxf(fmaxf(s[1][2], s[1][3]), fmaxf(fmaxf(s[2][0], s[2][1]), \
                      fmaxf(s[2][2], s[2][3])));                              \
    float pm2 = fmaxf(fmaxf(s[3][0], s[3][1]), fmaxf(s[3][2], s[3][3]));      \
    float pm = fmaxf(fmaxf(pm0, pm1), pm2);                                   \
    /* lazy rescale: cross-lane reduce only when some row max grew */         \
    if (__any(pm > m)){                                                       \
      pm = fmaxf(pm, __shfl_xor(pm, 16, 64));                                 \
      pm = fmaxf(pm, __shfl_xor(pm, 32, 64));                                 \
      const float nm = fmaxf(m, pm);                                          \
      const float corr = EXP2(m - nm);                                        \
      m = nm;                                                                 \
      lsum *= corr;                                                           \
      _Pragma("unroll")                                                       \
      for (int dt = 0; dt < 4; ++dt)                                          \
        _Pragma("unroll")                                                     \
        for (int r = 0; r < 4; ++r) oacc[dt][r] *= corr;                      \
    }                                                                         \
    float rs = 0.f;                                                           \
    _Pragma("unroll")                                                         \
    for (int ct = 0; ct < 4; ++ct){                                           \
      _Pragma("unroll")                                                       \
      for (int r = 0; r < 4; ++r){                                            \
        float p2 = EXP2(s[ct][r] - m);                                        \
        s[ct][r] = p2; rs += p2;                                              \
      }                                                                       \
    }                                                                         \
    lsum += rs;   /* per-lane partial; no shfl here */                        \
    _Pragma("unroll")                                                         \
    for (int ct = 0; ct < 4; ++ct){                                           \
      uint2 uv;                                                               \
      uv.x = cvtpk(s[ct][0], s[ct][1]);                                       \
      uv.y = cvtpk(s[ct][2], s[ct][3]);                                       \
      *(uint2*)(Pb + ((lr*128 + ct*32 + lg*8) ^ swz)) = uv;                   \
    }                                                                         \
    bf16x8 pa0 = __builtin_bit_cast(bf16x8, *(ushort8*)(Pb + ((lr*128      + lg*16) ^ swz))); \
    bf16x8 pa1 = __builtin_bit_cast(bf16x8, *(ushort8*)(Pb + ((lr*128 + 64 + lg*16) ^ swz))); \
    __builtin_amdgcn_s_setprio(1);                                            \
    _Pragma("unroll")                                                         \
    for (int dt = 0; dt < 4; ++dt){                                           \
      oacc[dt] = MFMA(ld8(VL + (dt*2)*512),   pa0, oacc[dt], 0, 0, 0);        \
      oacc[dt] = MFMA(ld8(VL + (dt*2+1)*512), pa1, oacc[dt], 0, 0, 0);        \
    }                                                                         \
    __builtin_amdgcn_s_setprio(0);                                            \
  }

  stage(0, 0);
  __syncthreads();                     // drains vmcnt -> tile 0 ready
  for (int kb2 = 0; kb2 < 64; kb2 += 2){
    stage(1, (kb2 + 1) & 63);          // issue next-tile loads (overlap compute)
    ITERBODY(kb2, 0)
    __syncthreads();                   // buf1 staged + all waves done with buf0
    stage(0, (kb2 + 2) & 63);
    ITERBODY(kb2 + 1, 1)
    __syncthreads();
  }
#undef ITERBODY

  // epilogue: single cross-lane sum reduce of the per-lane lsum partials
  lsum += __shfl_xor(lsum, 16, 64);
  lsum += __shfl_xor(lsum, 32, 64);
  const float inv = 1.0f / lsum;
  #pragma unroll
  for (int dt = 0; dt < 4; ++dt){
    ushort4v pk;
    #pragma unroll
    for (int r = 0; r < 4; ++r) pk[r] = f2bf(oacc[dt][r]*inv);
    *(ushort4v*)&Ob[(size_t)q*768 + h*64 + dt*16 + lg*4] = pk;
  }
}

// ---------------- proj GEMM: (4096x768)x(768x768) + b -> f32 out ----------------

__global__ __launch_bounds__(256) void k_proj(const u16* __restrict__ A, const u16* __restrict__ WT,
                                              const float* __restrict__ bias, float* __restrict__ out){
  __shared__ __align__(16) u16 At[128*64];
  __shared__ __align__(16) u16 Bt[128*64];
  const int tid = threadIdx.x, lane = tid & 63, w = tid >> 6;
  const int m0 = blockIdx.x*128, n0 = blockIdx.y*128;
  const int wr = (w >> 1)*64, wc = (w & 1)*64;
  const int lr = lane & 15, lg = lane >> 4;
  const int srcRow = w*32 + (lane >> 3);
  const int srcK   = (lane & 7)*8;
  f32x4 acc[4][4] = {};
  for (int kt = 0; kt < 12; ++kt){
    const int kbase = kt*64;
    for (int s = 0; s < 4; ++s){
      gload16(A  + (size_t)(m0 + srcRow + s*8)*768 + kbase + srcK, At + (w*32 + s*8)*64);
      gload16(WT + (size_t)(n0 + srcRow + s*8)*768 + kbase + srcK, Bt + (w*32 + s*8)*64);
    }
    __syncthreads();
    bf16x8 af[2][4], bfr[2][4];
    for (int ks = 0; ks < 2; ++ks)
      for (int i = 0; i < 4; ++i){
        af[ks][i]  = ld8(At + (wr + i*16 + lr)*64 + ks*32 + lg*8);
        bfr[ks][i] = ld8(Bt + (wc + i*16 + lr)*64 + ks*32 + lg*8);
      }
    for (int ks = 0; ks < 2; ++ks)
      for (int mi = 0; mi < 4; ++mi)
        for (int ni = 0; ni < 4; ++ni)
          acc[mi][ni] = MFMA(af[ks][mi], bfr[ks][ni], acc[mi][ni], 0, 0, 0);
    __syncthreads();
  }
  for (int mi = 0; mi < 4; ++mi)
    for (int ni = 0; ni < 4; ++ni){
      int col = n0 + wc + ni*16 + lr;
      float bv = bias[col];
      for (int r = 0; r < 4; ++r){
        int row = m0 + wr + mi*16 + lg*4 + r;
        out[(size_t)row*768 + col] = acc[mi][ni][r] + bv;
      }
    }
}

// ---------------- launch ----------------

extern "C" void kernel_launch(void* const* d_in, const int* in_sizes, int n_in,
                              void* d_out, int out_size, void* d_ws, size_t ws_size,
                              hipStream_t stream){
  const float* X32   = (const float*)d_in[0];
  const float* qkvw  = (const float*)d_in[1];
  const float* qkvb  = (const float*)d_in[2];
  const float* projw = (const float*)d_in[3];
  const float* projb = (const float*)d_in[4];
  const float* rposh = (const float*)d_in[5];
  const float* rposw = (const float*)d_in[6];

  u16* Xb  = (u16*)d_ws;            // 4096*768
  u16* W1T = Xb  + 3145728;         // 2304*768
  u16* PT  = W1T + 1769472;         // 768*768
  u16* Rh8 = PT  + 589824;          // 128*64 (padded)
  u16* Rw8 = Rh8 + 8192;            // 128*64 (padded)
  u16* Qs  = Rw8 + 8192;            // 12*4096*64 (pre-scaled by 1/8 * log2e)
  u16* Kf  = Qs  + 3145728;         // fragment-linear K [12][64][8][64][8]
  u16* Vf  = Kf  + 3145728;         // fragment-linear V^T [12][64][8][64][8]
  u16* Rlh = Vf  + 3145728;         // [12][4096][64]
  u16* Rlw = Rlh + 3145728;         // [12][4096][64]
  u16* Ob  = Rlw + 3145728;         // [4096][768]
  float* out = (float*)d_out;

  k_conv8  <<<1536, 256, 0, stream>>>(X32, Xb);
  k_tr     <<<dim3(12, 36), 256, 0, stream>>>(qkvw, W1T, 768, 2304);
  k_tr     <<<dim3(12, 12), 256, 0, stream>>>(projw, PT, 768, 768);
  k_relconv<<<64, 256, 0, stream>>>(rposh, rposw, Rh8, Rw8);
  k_qkv    <<<dim3(32, 18), 256, 0, stream>>>(Xb, W1T, qkvb, Qs, Kf, Vf);
  k_rel    <<<dim3(64, 12), 256, 0, stream>>>(Qs, Rh8, Rw8, Rlh, Rlw);
  k_flash  <<<768, 256, 0, stream>>>(Qs, Kf, Vf, Rlh, Rlw, Ob);
  k_proj   <<<dim3(32, 6), 256, 0, stream>>>(Ob, PT, projb, out);
}